// Round 2
// baseline (329.335 us; speedup 1.0000x reference)
//
#include <hip/hip_runtime.h>
#include <math.h>

// GaussianAdjacencyMatrix: out[b,i,j] = m*exp(-||x_i-x_j||^2/sigma^2) / (row_sum + 1e-8)
// B=8, N=2048, D=3.
// One wave per row; 8 rows (4 waves x 2) per block so the 24 KiB coordinate
// staging is amortized 8x and the row loop has zero barriers.

#define NN 2048
#define THREADS 256
#define WAVES (THREADS / 64)          // 4
#define ROWS_PER_WAVE 2
#define ROWS_PER_BLOCK (WAVES * ROWS_PER_WAVE)  // 8
#define EPS 1e-8f

__global__ __launch_bounds__(THREADS, 4) void gauss_adj_kernel(
    const float* __restrict__ coords,   // [B, N, 3]
    const float* __restrict__ masks,    // [B, N, N]
    const float* __restrict__ sigma,    // [1]
    float* __restrict__ out)            // [B, N, N]
{
    const int rows_base = blockIdx.x * ROWS_PER_BLOCK;   // global row index base
    const int b   = rows_base >> 11;                     // / 2048 (all 8 rows same batch)
    const int tid = threadIdx.x;
    const int wave = tid >> 6;
    const int lane = tid & 63;

    __shared__ __align__(16) float sx[NN];
    __shared__ __align__(16) float sy[NN];
    __shared__ __align__(16) float sz[NN];

    // stage this batch's coordinates SoA into LDS (24 KiB)
    const float* cb = coords + (size_t)b * NN * 3;
    for (int idx = tid; idx < NN; idx += THREADS) {
        sx[idx] = cb[idx * 3 + 0];
        sy[idx] = cb[idx * 3 + 1];
        sz[idx] = cb[idx * 3 + 2];
    }
    __syncthreads();

    const float s  = sigma[0];
    const float inv_s2 = 1.0f / (s * s);

    const float4* sx4 = (const float4*)sx;
    const float4* sy4 = (const float4*)sy;
    const float4* sz4 = (const float4*)sz;

    #pragma unroll
    for (int r = 0; r < ROWS_PER_WAVE; ++r) {
        const int row_local = wave * ROWS_PER_WAVE + r;
        const int row = rows_base + row_local;           // global row
        const int i   = (rows_base & (NN - 1)) + row_local;  // index within batch

        const float xi = sx[i];
        const float yi = sy[i];
        const float zi = sz[i];

        const float4* mrow = (const float4*)(masks + (size_t)row * NN);
        float4*       orow = (float4*)(out + (size_t)row * NN);

        float vals[32];                 // 8 chunks x 4
        float lsum = 0.0f;

        #pragma unroll
        for (int k = 0; k < 8; ++k) {
            const int j4 = k * 64 + lane;          // float4 index, coalesced per wave
            const float4 m = mrow[j4];
            const float4 X = sx4[j4];
            const float4 Y = sy4[j4];
            const float4 Z = sz4[j4];
            const float mx[4] = {m.x, m.y, m.z, m.w};
            const float xs[4] = {X.x, X.y, X.z, X.w};
            const float ys[4] = {Y.x, Y.y, Y.z, Y.w};
            const float zs[4] = {Z.x, Z.y, Z.z, Z.w};
            #pragma unroll
            for (int q = 0; q < 4; ++q) {
                const float dx = xi - xs[q];
                const float dy = yi - ys[q];
                const float dz = zi - zs[q];
                const float d  = dx * dx + dy * dy + dz * dz;
                const float a  = __expf(-d * inv_s2) * mx[q];
                vals[k * 4 + q] = a;
                lsum += a;
            }
        }

        // wave64 butterfly: every lane ends with the full row sum
        #pragma unroll
        for (int off = 1; off < 64; off <<= 1)
            lsum += __shfl_xor(lsum, off, 64);

        const float inv = 1.0f / (lsum + EPS);

        #pragma unroll
        for (int k = 0; k < 8; ++k) {
            const int j4 = k * 64 + lane;
            float4 o;
            o.x = vals[k * 4 + 0] * inv;
            o.y = vals[k * 4 + 1] * inv;
            o.z = vals[k * 4 + 2] * inv;
            o.w = vals[k * 4 + 3] * inv;
            orow[j4] = o;
        }
    }
}

extern "C" void kernel_launch(void* const* d_in, const int* in_sizes, int n_in,
                              void* d_out, int out_size, void* d_ws, size_t ws_size,
                              hipStream_t stream) {
    const float* coords = (const float*)d_in[0];   // [B,N,3]
    const float* masks  = (const float*)d_in[1];   // [B,N,N]
    const float* sigma  = (const float*)d_in[2];   // [1]
    float* out = (float*)d_out;

    const int B = in_sizes[0] / (NN * 3);
    const int rows = B * NN;
    gauss_adj_kernel<<<rows / ROWS_PER_BLOCK, THREADS, 0, stream>>>(coords, masks, sigma, out);
}

// Round 4
// 243.477 us; speedup vs baseline: 1.3526x; 1.3526x over previous
//
#include <hip/hip_runtime.h>
#include <math.h>

// GaussianAdjacencyMatrix: out[b,i,j] = m*exp(-||x_i-x_j||^2/sigma^2) / (row_sum + 1e-8)
// B=8, N=2048, D=3.
// Block = 256 threads handles 8 rows. Each thread owns 8 fixed columns
// (two float4 chunks); its columns' coords live in 24 registers, loaded once.
// vals[8]/thread (no spill). One barrier per row (double-buffered partials).
// Nontemporal output stores keep the 134 MB mask L3-resident.

#define NN 2048
#define THREADS 256
#define RPB 8
#define EPS 1e-8f

typedef float nfloat4 __attribute__((ext_vector_type(4)));  // native vec for nt-store

__global__ __launch_bounds__(THREADS) void gauss_adj_kernel(
    const float* __restrict__ coords,   // [B, N, 3]
    const float* __restrict__ masks,    // [B, N, N]
    const float* __restrict__ sigma,    // [1]
    float* __restrict__ out)            // [B, N, N]
{
    const int rows_base = blockIdx.x * RPB;
    const int b   = rows_base >> 11;           // / 2048
    const int ib  = rows_base & (NN - 1);      // first row index within batch
    const int tid = threadIdx.x;
    const int wave = tid >> 6;
    const int lane = tid & 63;

    __shared__ float srow[RPB * 3];   // this block's 8 row-centers (x,y,z)
    __shared__ float red[2][4];       // double-buffered per-wave partial sums

    const float* cb = coords + (size_t)b * NN * 3;
    if (tid < RPB * 3) srow[tid] = cb[ib * 3 + tid];

    // This thread's 8 columns: chunks j4 = c*256+tid (c=0,1), cols 4*j4..4*j4+3.
    // Their coords = float4s 3*j4, 3*j4+1, 3*j4+2 (48 B per chunk, coalesced).
    const float4* cb4 = (const float4*)cb;
    float xs[2][4], ys[2][4], zs[2][4];
    #pragma unroll
    for (int c = 0; c < 2; ++c) {
        const int j4 = c * THREADS + tid;
        const float4 f0 = cb4[3 * j4 + 0];
        const float4 f1 = cb4[3 * j4 + 1];
        const float4 f2 = cb4[3 * j4 + 2];
        xs[c][0] = f0.x; ys[c][0] = f0.y; zs[c][0] = f0.z;
        xs[c][1] = f0.w; ys[c][1] = f1.x; zs[c][1] = f1.y;
        xs[c][2] = f1.z; ys[c][2] = f1.w; zs[c][2] = f2.x;
        xs[c][3] = f2.y; ys[c][3] = f2.z; zs[c][3] = f2.w;
    }

    const float s = sigma[0];
    const float inv_s2 = 1.0f / (s * s);

    __syncthreads();   // srow ready

    for (int r = 0; r < RPB; ++r) {
        const int row = rows_base + r;
        const float xi = srow[r * 3 + 0];
        const float yi = srow[r * 3 + 1];
        const float zi = srow[r * 3 + 2];

        const float4* mrow = (const float4*)(masks + (size_t)row * NN);

        float vals[2][4];
        float lsum = 0.0f;
        #pragma unroll
        for (int c = 0; c < 2; ++c) {
            const float4 m = mrow[c * THREADS + tid];
            const float mm[4] = {m.x, m.y, m.z, m.w};
            #pragma unroll
            for (int q = 0; q < 4; ++q) {
                const float dx = xi - xs[c][q];
                const float dy = yi - ys[c][q];
                const float dz = zi - zs[c][q];
                const float a = __expf(-(dx * dx + dy * dy + dz * dz) * inv_s2) * mm[q];
                vals[c][q] = a;
                lsum += a;
            }
        }

        // wave64 butterfly, then one barrier for the cross-wave sum
        #pragma unroll
        for (int off = 1; off < 64; off <<= 1)
            lsum += __shfl_xor(lsum, off, 64);
        if (lane == 0) red[r & 1][wave] = lsum;
        __syncthreads();
        const float tot = red[r & 1][0] + red[r & 1][1] + red[r & 1][2] + red[r & 1][3];
        const float inv = 1.0f / (tot + EPS);

        nfloat4* orow = (nfloat4*)(out + (size_t)row * NN);
        #pragma unroll
        for (int c = 0; c < 2; ++c) {
            nfloat4 o;
            o.x = vals[c][0] * inv;
            o.y = vals[c][1] * inv;
            o.z = vals[c][2] * inv;
            o.w = vals[c][3] * inv;
            __builtin_nontemporal_store(o, &orow[c * THREADS + tid]);
        }
    }
}

extern "C" void kernel_launch(void* const* d_in, const int* in_sizes, int n_in,
                              void* d_out, int out_size, void* d_ws, size_t ws_size,
                              hipStream_t stream) {
    const float* coords = (const float*)d_in[0];   // [B,N,3]
    const float* masks  = (const float*)d_in[1];   // [B,N,N]
    const float* sigma  = (const float*)d_in[2];   // [1]
    float* out = (float*)d_out;

    const int B = in_sizes[0] / (NN * 3);
    const int rows = B * NN;
    gauss_adj_kernel<<<rows / RPB, THREADS, 0, stream>>>(coords, masks, sigma, out);
}